// Round 3
// baseline (6236.782 us; speedup 1.0000x reference)
//
#include <hip/hip_runtime.h>
#include <hip/hip_bf16.h>

#define N_ROWS   32768
#define DIM      512
#define K_CODES  8192
#define BETA     0.01f

// d_out layout (floats): [quantized 16777216][loss 1][indices-as-float 32768]
#define LOSS_OFF 16777216
#define IDX_OFF  16777217

// d_ws layout (4-byte units): xx[32768] | idx[32768] | partial[8192] | cnt[1] | list[32768]
#define WS_XX_OFF     0
#define WS_IDX_OFF    32768
#define WS_PART_OFF   65536
#define WS_CNT_OFF    73728
#define WS_LIST_OFF   73729

#define FLT_BIG 3.402823466e+38f
#define WINDOW  6.2e-5f   // one quantization bin (ulp near 512) + slack
#define BTOL    5e-7f     // covers worst-case fp32 dot accumulation error (~1.3e-7) w/ margin

// ---------------------------------------------------------------- kernel XX
// xx[n] = fp32 sum of squares of row n, replicating numpy pairwise_sum EXACTLY:
// n=512 -> (B0+B1)+(B2+B3), each B = base-case over 128 elems with 8 accumulators:
// r[j]=a[j]; for i=8..120 step 8: r[j]+=a[i+j]; ((r0+r1)+(r2+r3))+((r4+r5)+(r6+r7)).
__global__ __launch_bounds__(256) void vq_xx_kernel(const float* __restrict__ x,
                                                    float* __restrict__ xx) {
    __shared__ float l[4][512];
    const int wave = threadIdx.x >> 6;
    const int lane = threadIdx.x & 63;
    const int row = blockIdx.x * 4 + wave;
    const float* xr = x + (size_t)row * DIM;
#pragma unroll
    for (int i = 0; i < 2; ++i) {
        float4 v = *reinterpret_cast<const float4*>(xr + lane * 8 + i * 4);
        float4 q = make_float4(v.x * v.x, v.y * v.y, v.z * v.z, v.w * v.w);
        *reinterpret_cast<float4*>(&l[wave][lane * 8 + i * 4]) = q;
    }
    __syncthreads();
    if (lane == 0) {
        float B[4];
#pragma unroll
        for (int q = 0; q < 4; ++q) {
            const float* a = &l[wave][q * 128];
            float r0 = a[0], r1 = a[1], r2 = a[2], r3 = a[3];
            float r4 = a[4], r5 = a[5], r6 = a[6], r7 = a[7];
            for (int i = 8; i < 128; i += 8) {
                r0 += a[i + 0]; r1 += a[i + 1]; r2 += a[i + 2]; r3 += a[i + 3];
                r4 += a[i + 4]; r5 += a[i + 5]; r6 += a[i + 6]; r7 += a[i + 7];
            }
            B[q] = ((r0 + r1) + (r2 + r3)) + ((r4 + r5) + (r6 + r7));
        }
        xx[row] = (B[0] + B[1]) + (B[2] + B[3]);
    }
}

// ---------------------------------------------------------------- kernel B
// Fused distance GEMM + fp32-quantized argmin (replicating the reference's
// fl32(xx - 2*dot) rounding), with bin-boundary-proximity flagging.
#define TN 128
#define TK 256
#define DC 64

__global__ __launch_bounds__(512) void vq_argmin_kernel(
    const float* __restrict__ x, const float* __restrict__ cb,
    const float* __restrict__ xx, float* __restrict__ outIdxF,
    int* __restrict__ idxI, int* __restrict__ cnt, int* __restrict__ list) {
    __shared__ float xs[TN][DC];   // 32 KB
    __shared__ float es[DC][TK];   // 64 KB

    const int t = threadIdx.x;
    const int tx = t & 31;   // 32 groups x 8 codes = 256
    const int ty = t >> 5;   // 16 groups x 8 rows  = 128
    const int rowBase = blockIdx.x * TN;

    float xxr[8];
#pragma unroll
    for (int i = 0; i < 8; ++i) xxr[i] = xx[rowBase + ty * 8 + i];

    float minv[8], minb[8];
    int mini[8];
#pragma unroll
    for (int i = 0; i < 8; ++i) { minv[i] = FLT_BIG; minb[i] = FLT_BIG; mini[i] = 0; }

    for (int k0 = 0; k0 < K_CODES; k0 += TK) {
        float acc[8][8];
#pragma unroll
        for (int i = 0; i < 8; ++i)
#pragma unroll
            for (int j = 0; j < 8; ++j) acc[i][j] = 0.f;

        for (int d0 = 0; d0 < DIM; d0 += DC) {
            __syncthreads();
#pragma unroll
            for (int i = 0; i < 4; ++i) {
                int f = t + i * 512;
                int r = f >> 4;
                int q = f & 15;
                float4 v = *reinterpret_cast<const float4*>(
                    x + (size_t)(rowBase + r) * DIM + d0 + q * 4);
                *reinterpret_cast<float4*>(&xs[r][q * 4]) = v;
            }
#pragma unroll
            for (int i = 0; i < 8; ++i) {
                int f = t + i * 512;
                int c = f >> 4;
                int q = f & 15;
                float4 v = *reinterpret_cast<const float4*>(
                    cb + (size_t)(k0 + c) * DIM + d0 + q * 4);
                es[q * 4 + 0][c] = v.x;
                es[q * 4 + 1][c] = v.y;
                es[q * 4 + 2][c] = v.z;
                es[q * 4 + 3][c] = v.w;
            }
            __syncthreads();
#pragma unroll 4
            for (int dd = 0; dd < DC; ++dd) {
                float xv[8], ev[8];
#pragma unroll
                for (int i = 0; i < 8; ++i) xv[i] = xs[ty * 8 + i][dd];
                float4 a = *reinterpret_cast<const float4*>(&es[dd][tx * 8]);
                float4 b = *reinterpret_cast<const float4*>(&es[dd][tx * 8 + 4]);
                ev[0] = a.x; ev[1] = a.y; ev[2] = a.z; ev[3] = a.w;
                ev[4] = b.x; ev[5] = b.y; ev[6] = b.z; ev[7] = b.w;
#pragma unroll
                for (int i = 0; i < 8; ++i)
#pragma unroll
                    for (int j = 0; j < 8; ++j)
                        acc[i][j] = fmaf(xv[i], ev[j], acc[i][j]);
            }
        }
        // Epilogue: s = fl32(xx - 2*acc)  (x2 exact; one fp32 subtract = ref rounding).
        // beta = distance of (xx - 2*acc) to the nearest fp32 rounding boundary.
#pragma unroll
        for (int i = 0; i < 8; ++i) {
#pragma unroll
            for (int j = 0; j < 8; ++j) {
                float cc = 2.0f * acc[i][j];
                float s = xxr[i] - cc;
                double v = (double)xxr[i] - (double)cc;
                double r = v - (double)s;
                unsigned au = __float_as_uint(s);
                float ulp_hi = __uint_as_float(au + 1) - s;
                float ulp_lo = s - __uint_as_float(au - 1);
                double beta = fmin((double)(0.5f * ulp_hi) - r,
                                   r + (double)(0.5f * ulp_lo));
                float bf = (float)beta;
                int idx = k0 + tx * 8 + j;
                if (s < minv[i]) { minv[i] = s; mini[i] = idx; minb[i] = bf; }
                else if (s == minv[i]) { minb[i] = fminf(minb[i], bf); }
            }
        }
    }

    // cross-thread reduce over 32 tx groups per row (lexicographic: first index wins)
    __syncthreads();
    float* redv = &xs[0][0];                           // 4096 floats
    int* redi = reinterpret_cast<int*>(&es[0][0]);     // 4096 ints
    float* rowMinL = &xs[0][0] + 4096;                 // 128 floats
    int* flagL = reinterpret_cast<int*>(&es[0][0]) + 4096;  // 128 ints
#pragma unroll
    for (int i = 0; i < 8; ++i) {
        int slot = (ty * 8 + i) * 32 + tx;
        redv[slot] = minv[i];
        redi[slot] = mini[i];
    }
    __syncthreads();
    if (t < TN) {
        float M1 = FLT_BIG;
        int I1 = 0x7fffffff;
#pragma unroll 8
        for (int j = 0; j < 32; ++j) {
            float v = redv[t * 32 + j];
            int ix = redi[t * 32 + j];
            if (v < M1 || (v == M1 && ix < I1)) { M1 = v; I1 = ix; }
        }
        const int row = rowBase + t;
        idxI[row] = I1;
        outIdxF[row] = (float)I1;
        rowMinL[t] = M1;
        flagL[t] = 0;
    }
    __syncthreads();
#pragma unroll
    for (int i = 0; i < 8; ++i) {
        int slot = ty * 8 + i;
        if (minv[i] <= rowMinL[slot] + WINDOW && minb[i] < BTOL) flagL[slot] = 1;
    }
    __syncthreads();
    if (t < TN && flagL[t]) {
        int pos = atomicAdd(cnt, 1);
        list[pos] = rowBase + t;
    }
}

// ---------------------------------------------------------------- kernel B2
// Re-rank flagged rows: c = fl32(2 * fp64-exact dot), s = fl32(xx - c),
// quantized argmin with first-index tie-break.
__global__ __launch_bounds__(256) void vq_fixup_kernel(
    const float* __restrict__ x, const float* __restrict__ cb,
    const float* __restrict__ xx, const int* __restrict__ cnt,
    const int* __restrict__ list, float* __restrict__ outIdxF,
    int* __restrict__ idxI) {
    __shared__ float xr[DIM];
    __shared__ float rv[256];
    __shared__ int ri[256];
    const int t = threadIdx.x;
    const int nflag = *cnt;
    for (int it = blockIdx.x; it < nflag; it += gridDim.x) {
        const int row = list[it];
        __syncthreads();                 // protect xr/rv reuse across iterations
        xr[t] = x[(size_t)row * DIM + t];
        xr[t + 256] = x[(size_t)row * DIM + 256 + t];
        __syncthreads();
        const float xxrow = xx[row];
        float best = FLT_BIG;
        int bi = 0x7fffffff;
        for (int k = t; k < K_CODES; k += 256) {
            const float* er = cb + (size_t)k * DIM;
            double xe0 = 0.0, xe1 = 0.0, xe2d = 0.0, xe3 = 0.0;
            for (int d = 0; d < DIM; d += 4) {
                float4 ev = *reinterpret_cast<const float4*>(er + d);
                xe0 = fma((double)xr[d + 0], (double)ev.x, xe0);
                xe1 = fma((double)xr[d + 1], (double)ev.y, xe1);
                xe2d = fma((double)xr[d + 2], (double)ev.z, xe2d);
                xe3 = fma((double)xr[d + 3], (double)ev.w, xe3);
            }
            double xe = (xe0 + xe1) + (xe2d + xe3);
            float c = (float)(2.0 * xe);
            float s = xxrow - c;
            if (s < best) { best = s; bi = k; }   // k ascending per thread -> tie-low
        }
        rv[t] = best; ri[t] = bi;
        __syncthreads();
        for (int off = 128; off > 0; off >>= 1) {
            if (t < off) {
                float ov = rv[t + off]; int oi = ri[t + off];
                if (ov < rv[t] || (ov == rv[t] && oi < ri[t])) { rv[t] = ov; ri[t] = oi; }
            }
            __syncthreads();
        }
        if (t == 0) {
            idxI[row] = ri[0];
            outIdxF[row] = (float)ri[0];
        }
    }
}

// ---------------------------------------------------------------- kernel C
__global__ __launch_bounds__(256) void vq_gather_kernel(
    const float* __restrict__ x, const float* __restrict__ cb,
    const int* __restrict__ idxI, float* __restrict__ outQ,
    float* __restrict__ partial) {
    const int wave = threadIdx.x >> 6;
    const int lane = threadIdx.x & 63;
    const int row = blockIdx.x * 4 + wave;
    const int code = idxI[row];
    const float* xr = x + (size_t)row * DIM;
    const float* er = cb + (size_t)code * DIM;
    float* qr = outQ + (size_t)row * DIM;
    float s = 0.f;
#pragma unroll
    for (int i = 0; i < 2; ++i) {
        int d = lane * 8 + i * 4;
        float4 xv = *reinterpret_cast<const float4*>(xr + d);
        float4 ev = *reinterpret_cast<const float4*>(er + d);
        float4 dv = make_float4(ev.x - xv.x, ev.y - xv.y, ev.z - xv.z, ev.w - xv.w);
        *reinterpret_cast<float4*>(qr + d) = ev;   // x + (q - x) ~= q (within 2% thr)
        s += dv.x * dv.x + dv.y * dv.y + dv.z * dv.z + dv.w * dv.w;
    }
#pragma unroll
    for (int off = 32; off > 0; off >>= 1) s += __shfl_xor(s, off);
    __shared__ float ws4[4];
    if (lane == 0) ws4[wave] = s;
    __syncthreads();
    if (threadIdx.x == 0)
        partial[blockIdx.x] = (ws4[0] + ws4[1]) + (ws4[2] + ws4[3]);
}

// ---------------------------------------------------------------- kernel D
__global__ __launch_bounds__(256) void vq_loss_kernel(const float* __restrict__ partial,
                                                      float* __restrict__ outLoss) {
    float s = 0.f;
    for (int i = threadIdx.x; i < 8192; i += 256) s += partial[i];
    __shared__ float sm[256];
    sm[threadIdx.x] = s;
    __syncthreads();
    for (int off = 128; off > 0; off >>= 1) {
        if (threadIdx.x < off) sm[threadIdx.x] += sm[threadIdx.x + off];
        __syncthreads();
    }
    if (threadIdx.x == 0)
        outLoss[0] = sm[0] * (1.0f + BETA) / 16777216.0f;
}

// ---------------------------------------------------------------- launch
extern "C" void kernel_launch(void* const* d_in, const int* in_sizes, int n_in,
                              void* d_out, int out_size, void* d_ws, size_t ws_size,
                              hipStream_t stream) {
    const float* x = (const float*)d_in[0];   // [32768, 512]
    const float* cb = (const float*)d_in[1];  // [8192, 512]
    float* out = (float*)d_out;

    float* xx = (float*)d_ws + WS_XX_OFF;
    int* idxI = (int*)d_ws + WS_IDX_OFF;
    float* partial = (float*)d_ws + WS_PART_OFF;
    int* cnt = (int*)d_ws + WS_CNT_OFF;
    int* list = (int*)d_ws + WS_LIST_OFF;

    hipMemsetAsync(cnt, 0, sizeof(int), stream);
    hipLaunchKernelGGL(vq_xx_kernel, dim3(N_ROWS / 4), dim3(256), 0, stream, x, xx);
    hipLaunchKernelGGL(vq_argmin_kernel, dim3(N_ROWS / TN), dim3(512), 0, stream,
                       x, cb, xx, out + IDX_OFF, idxI, cnt, list);
    hipLaunchKernelGGL(vq_fixup_kernel, dim3(256), dim3(256), 0, stream,
                       x, cb, xx, cnt, list, out + IDX_OFF, idxI);
    hipLaunchKernelGGL(vq_gather_kernel, dim3(N_ROWS / 4), dim3(256), 0, stream,
                       x, cb, idxI, out, partial);
    hipLaunchKernelGGL(vq_loss_kernel, dim3(1), dim3(256), 0, stream,
                       partial, out + LOSS_OFF);
}

// Round 4
// 660.741 us; speedup vs baseline: 9.4391x; 9.4391x over previous
//
#include <hip/hip_runtime.h>
#include <hip/hip_bf16.h>
#include <hip/hip_fp16.h>

typedef unsigned short ushortT;
typedef _Float16 half8 __attribute__((ext_vector_type(8)));
typedef float f32x4 __attribute__((ext_vector_type(4)));

#define N_ROWS   32768
#define DIM      512
#define K_CODES  8192
#define BETA     0.01f

// d_out layout (floats): [quantized 16777216][loss 1][indices-as-float 32768]
#define LOSS_OFF 16777216
#define IDX_OFF  16777217

// d_out-as-scratch (floats offsets). Legal: vq_gather rewrites [0,16.7M) last.
#define SC_XH_F    0            // 32768*512 halves = 8M floats
#define SC_EH_F    8388608      // 8192*512 halves  = 2M floats
#define SC_GCODE_F 10485760     // 32768*16 u32
#define SC_GCNT_F  11010048     // 32768 u32

// d_ws layout (4-byte units): xx[32768] | idx[32768] | partial[8192] | cnt[1] | list[32768]
#define WS_XX_OFF     0
#define WS_IDX_OFF    32768
#define WS_PART_OFF   65536
#define WS_CNT_OFF    73728
#define WS_LIST_OFF   73729

#define FLT_BIG 3.402823466e+38f
#define W_CAND  1.0e-4f          // bin(6.2e-5) + ref slack + 2x fp16-split err
#define NSC     (-0.001953125f)  // -2/1024 (eh scaled by 1024), exact
#define CAP     24
#define GCAP    16

typedef __attribute__((address_space(1))) const unsigned int GUI;
typedef __attribute__((address_space(3))) unsigned int LUI;
__device__ __forceinline__ void gload16(const void* g, void* l) {
    __builtin_amdgcn_global_load_lds((GUI*)g, (LUI*)l, 16, 0, 0);
}

// ---------------------------------------------------------------- prep
// xh = fp16(x); eh = fp16(1024*e). 8 f32 -> 8 halves per thread.
__global__ __launch_bounds__(256) void vq_prep(const float* __restrict__ x,
                                               const float* __restrict__ cb,
                                               ushortT* __restrict__ xh,
                                               ushortT* __restrict__ eh) {
    const size_t gid = (size_t)blockIdx.x * 256 + threadIdx.x;
    const size_t off8 = gid * 8;
    const float* src;
    ushortT* dst;
    float sc;
    if (off8 < 16777216UL) { src = x + off8; dst = xh + off8; sc = 1.0f; }
    else { size_t o = off8 - 16777216UL; src = cb + o; dst = eh + o; sc = 1024.0f; }
    float4 v0 = *reinterpret_cast<const float4*>(src);
    float4 v1 = *reinterpret_cast<const float4*>(src + 4);
    union { ushortT s[8]; uint4 v; } u;
    u.s[0] = __half_as_ushort(__float2half(v0.x * sc));
    u.s[1] = __half_as_ushort(__float2half(v0.y * sc));
    u.s[2] = __half_as_ushort(__float2half(v0.z * sc));
    u.s[3] = __half_as_ushort(__float2half(v0.w * sc));
    u.s[4] = __half_as_ushort(__float2half(v1.x * sc));
    u.s[5] = __half_as_ushort(__float2half(v1.y * sc));
    u.s[6] = __half_as_ushort(__float2half(v1.z * sc));
    u.s[7] = __half_as_ushort(__float2half(v1.w * sc));
    *reinterpret_cast<uint4*>(dst) = u.v;
}

// ---------------------------------------------------------------- kernel XX
// xx[n] replicating numpy pairwise_sum exactly (proven in round 3).
__global__ __launch_bounds__(256) void vq_xx_kernel(const float* __restrict__ x,
                                                    float* __restrict__ xx) {
    __shared__ float l[4][512];
    const int wave = threadIdx.x >> 6;
    const int lane = threadIdx.x & 63;
    const int row = blockIdx.x * 4 + wave;
    const float* xr = x + (size_t)row * DIM;
#pragma unroll
    for (int i = 0; i < 2; ++i) {
        float4 v = *reinterpret_cast<const float4*>(xr + lane * 8 + i * 4);
        float4 q = make_float4(v.x * v.x, v.y * v.y, v.z * v.z, v.w * v.w);
        *reinterpret_cast<float4*>(&l[wave][lane * 8 + i * 4]) = q;
    }
    __syncthreads();
    if (lane == 0) {
        float B[4];
#pragma unroll
        for (int q = 0; q < 4; ++q) {
            const float* a = &l[wave][q * 128];
            float r0 = a[0], r1 = a[1], r2 = a[2], r3 = a[3];
            float r4 = a[4], r5 = a[5], r6 = a[6], r7 = a[7];
            for (int i = 8; i < 128; i += 8) {
                r0 += a[i + 0]; r1 += a[i + 1]; r2 += a[i + 2]; r3 += a[i + 3];
                r4 += a[i + 4]; r5 += a[i + 5]; r6 += a[i + 6]; r7 += a[i + 7];
            }
            B[q] = ((r0 + r1) + (r2 + r3)) + ((r4 + r5) + (r6 + r7));
        }
        xx[row] = (B[0] + B[1]) + (B[2] + B[3]);
    }
}

// ---------------------------------------------------------------- kernel M
// fp16 MFMA candidate pass. BM=128 x BN=256 tile, BK=64, 8 waves (2x4),
// 4x4 16x16x32 fragments/wave. Pre-swizzled global source + swizzled ds_read.
#define BM 128
#define BN 256
#define BKH 64

__global__ __launch_bounds__(512, 2) void vq_margmin(
    const ushortT* __restrict__ xh, const ushortT* __restrict__ eh,
    const float* __restrict__ xx,
    unsigned* __restrict__ gCode, unsigned* __restrict__ gCnt,
    int* __restrict__ fixcnt, int* __restrict__ fixlist) {
    __shared__ ushortT As[BM * BKH];      // 16 KB
    __shared__ ushortT Bs[BN * BKH];      // 32 KB
    __shared__ unsigned RminU[BM];
    __shared__ unsigned Ccnt[BM];
    __shared__ ushortT Ccode[BM * CAP];   // 6 KB
    __shared__ float  Cscore[BM * CAP];   // 12 KB

    const int t = threadIdx.x;
    const int l = t & 63;
    const int wid = t >> 6;
    const int wm = wid >> 2;      // 0..1 : 64-row region
    const int wn = wid & 3;       // 0..3 : 64-col region
    const int lr = l & 15;
    const int lg = l >> 4;
    const int rowBase = blockIdx.x * BM;

    if (t < BM) { RminU[t] = 0x7f7fffffu; Ccnt[t] = 0u; }

    float xxr[4][4];
#pragma unroll
    for (int mf = 0; mf < 4; ++mf)
#pragma unroll
        for (int r = 0; r < 4; ++r)
            xxr[mf][r] = xx[rowBase + wm * 64 + mf * 16 + lg * 4 + r];

    __syncthreads();

    for (int k0t = 0; k0t < K_CODES / BN; ++k0t) {
        const int k0 = k0t * BN;
        f32x4 acc[4][4];
#pragma unroll
        for (int mf = 0; mf < 4; ++mf)
#pragma unroll
            for (int nf = 0; nf < 4; ++nf)
                acc[mf][nf] = (f32x4){0.f, 0.f, 0.f, 0.f};

        for (int kt = 0; kt < DIM; kt += BKH) {
            // stage A: 1024 16B chunks (swizzled source, linear LDS dest)
#pragma unroll
            for (int i = 0; i < 2; ++i) {
                int f = t + i * 512;
                int r = f >> 3, g = f & 7;
                int gs = g ^ (r & 7);
                gload16(xh + (size_t)(rowBase + r) * DIM + kt + gs * 8, As + f * 8);
            }
            // stage B: 2048 chunks
#pragma unroll
            for (int i = 0; i < 4; ++i) {
                int f = t + i * 512;
                int r = f >> 3, g = f & 7;
                int gs = g ^ (r & 7);
                gload16(eh + (size_t)(k0 + r) * DIM + kt + gs * 8, Bs + f * 8);
            }
            __syncthreads();
#pragma unroll
            for (int ks8 = 0; ks8 < 8; ks8 += 4) {   // two K=32 substeps
                half8 a[4], b[4];
#pragma unroll
                for (int mf = 0; mf < 4; ++mf) {
                    int row = wm * 64 + mf * 16 + lr;
                    int pg = (ks8 + lg) ^ (row & 7);
                    a[mf] = *reinterpret_cast<const half8*>(As + row * BKH + pg * 8);
                }
#pragma unroll
                for (int nf = 0; nf < 4; ++nf) {
                    int col = wn * 64 + nf * 16 + lr;
                    int pg = (ks8 + lg) ^ (col & 7);
                    b[nf] = *reinterpret_cast<const half8*>(Bs + col * BKH + pg * 8);
                }
#pragma unroll
                for (int mf = 0; mf < 4; ++mf)
#pragma unroll
                    for (int nf = 0; nf < 4; ++nf)
                        acc[mf][nf] = __builtin_amdgcn_mfma_f32_16x16x32_f16(
                            a[mf], b[nf], acc[mf][nf], 0, 0, 0);
            }
            __syncthreads();
        }
        // epilogue: s = xx - acc*2/1024 ; per-row running min + candidate insert
#pragma unroll
        for (int mf = 0; mf < 4; ++mf) {
#pragma unroll
            for (int r = 0; r < 4; ++r) {
                float s0 = fmaf(NSC, acc[mf][0][r], xxr[mf][r]);
                float s1 = fmaf(NSC, acc[mf][1][r], xxr[mf][r]);
                float s2 = fmaf(NSC, acc[mf][2][r], xxr[mf][r]);
                float s3 = fmaf(NSC, acc[mf][3][r], xxr[mf][r]);
                float v = fminf(fminf(s0, s1), fminf(s2, s3));
                v = fminf(v, __shfl_xor(v, 1));
                v = fminf(v, __shfl_xor(v, 2));
                v = fminf(v, __shfl_xor(v, 4));
                v = fminf(v, __shfl_xor(v, 8));
                const int row = wm * 64 + mf * 16 + lg * 4 + r;
                unsigned old = atomicMin(&RminU[row], __float_as_uint(v));
                float thr = fminf(__uint_as_float(old), v) + W_CAND;
                if (s0 <= thr) {
                    unsigned sl = atomicAdd(&Ccnt[row], 1u);
                    if (sl < CAP) { Ccode[row*CAP+sl] = (ushortT)(k0 + wn*64 + 0*16 + lr); Cscore[row*CAP+sl] = s0; }
                }
                if (s1 <= thr) {
                    unsigned sl = atomicAdd(&Ccnt[row], 1u);
                    if (sl < CAP) { Ccode[row*CAP+sl] = (ushortT)(k0 + wn*64 + 1*16 + lr); Cscore[row*CAP+sl] = s1; }
                }
                if (s2 <= thr) {
                    unsigned sl = atomicAdd(&Ccnt[row], 1u);
                    if (sl < CAP) { Ccode[row*CAP+sl] = (ushortT)(k0 + wn*64 + 2*16 + lr); Cscore[row*CAP+sl] = s2; }
                }
                if (s3 <= thr) {
                    unsigned sl = atomicAdd(&Ccnt[row], 1u);
                    if (sl < CAP) { Ccode[row*CAP+sl] = (ushortT)(k0 + wn*64 + 3*16 + lr); Cscore[row*CAP+sl] = s3; }
                }
            }
        }
    }
    __syncthreads();
    if (t < BM) {
        const int grow = rowBase + t;
        float m = __uint_as_float(RminU[t]);
        unsigned cc = Ccnt[t];
        bool ovf = (cc > CAP);
        unsigned outc = 0;
        if (!ovf) {
            for (unsigned j = 0; j < cc; ++j) {
                if (Cscore[t * CAP + j] <= m + W_CAND) {
                    if (outc < GCAP) gCode[(size_t)grow * GCAP + outc++] = Ccode[t * CAP + j];
                    else { ovf = true; break; }
                }
            }
        }
        if (ovf) {
            gCnt[grow] = 0xFFFFFFFFu;
            int pos = atomicAdd(fixcnt, 1);
            fixlist[pos] = grow;
        } else {
            gCnt[grow] = outc;
        }
    }
}

// ---------------------------------------------------------------- refine
// fp64-exact dots for each candidate, quantized compare s=fl32(xx-(f32)(2*dot)),
// first-index tie-break. One wave per row.
__global__ __launch_bounds__(256) void vq_refine(
    const float* __restrict__ x, const float* __restrict__ cb,
    const float* __restrict__ xx, const unsigned* __restrict__ gCode,
    const unsigned* __restrict__ gCnt, float* __restrict__ outIdxF,
    int* __restrict__ idxI) {
    const int wave = threadIdx.x >> 6;
    const int lane = threadIdx.x & 63;
    const int row = blockIdx.x * 4 + wave;
    const unsigned cc = gCnt[row];
    if (cc == 0xFFFFFFFFu) return;   // full fixup handles this row
    const float* xr = x + (size_t)row * DIM;
    float4 xa = *reinterpret_cast<const float4*>(xr + lane * 8);
    float4 xb = *reinterpret_cast<const float4*>(xr + lane * 8 + 4);
    const float xxrow = xx[row];
    float best = FLT_BIG;
    int bi = 0x7fffffff;
    for (unsigned c = 0; c < cc; ++c) {
        int code = (int)gCode[(size_t)row * GCAP + c];
        const float* er = cb + (size_t)code * DIM;
        float4 ea = *reinterpret_cast<const float4*>(er + lane * 8);
        float4 eb = *reinterpret_cast<const float4*>(er + lane * 8 + 4);
        double p = (double)xa.x * ea.x + (double)xa.y * ea.y
                 + (double)xa.z * ea.z + (double)xa.w * ea.w
                 + (double)xb.x * eb.x + (double)xb.y * eb.y
                 + (double)xb.z * eb.z + (double)xb.w * eb.w;
#pragma unroll
        for (int off = 1; off < 64; off <<= 1) p += __shfl_xor(p, off);
        float sc = xxrow - (float)(2.0 * p);
        if (sc < best || (sc == best && code < bi)) { best = sc; bi = code; }
    }
    if (lane == 0) { idxI[row] = bi; outIdxF[row] = (float)bi; }
}

// ---------------------------------------------------------------- fixup
// Full 8192-code re-rank for overflow rows (expected ~0). Round-3 proven.
__global__ __launch_bounds__(256) void vq_fixup_kernel(
    const float* __restrict__ x, const float* __restrict__ cb,
    const float* __restrict__ xx, const int* __restrict__ cnt,
    const int* __restrict__ list, float* __restrict__ outIdxF,
    int* __restrict__ idxI) {
    __shared__ float xr[DIM];
    __shared__ float rv[256];
    __shared__ int ri[256];
    const int t = threadIdx.x;
    const int nflag = *cnt;
    for (int it = blockIdx.x; it < nflag; it += gridDim.x) {
        const int row = list[it];
        __syncthreads();
        xr[t] = x[(size_t)row * DIM + t];
        xr[t + 256] = x[(size_t)row * DIM + 256 + t];
        __syncthreads();
        const float xxrow = xx[row];
        float best = FLT_BIG;
        int bi = 0x7fffffff;
        for (int k = t; k < K_CODES; k += 256) {
            const float* er = cb + (size_t)k * DIM;
            double xe0 = 0.0, xe1 = 0.0, xe2d = 0.0, xe3 = 0.0;
            for (int d = 0; d < DIM; d += 4) {
                float4 ev = *reinterpret_cast<const float4*>(er + d);
                xe0 = fma((double)xr[d + 0], (double)ev.x, xe0);
                xe1 = fma((double)xr[d + 1], (double)ev.y, xe1);
                xe2d = fma((double)xr[d + 2], (double)ev.z, xe2d);
                xe3 = fma((double)xr[d + 3], (double)ev.w, xe3);
            }
            double xe = (xe0 + xe1) + (xe2d + xe3);
            float c = (float)(2.0 * xe);
            float s = xxrow - c;
            if (s < best) { best = s; bi = k; }
        }
        rv[t] = best; ri[t] = bi;
        __syncthreads();
        for (int off = 128; off > 0; off >>= 1) {
            if (t < off) {
                float ov = rv[t + off]; int oi = ri[t + off];
                if (ov < rv[t] || (ov == rv[t] && oi < ri[t])) { rv[t] = ov; ri[t] = oi; }
            }
            __syncthreads();
        }
        if (t == 0) {
            idxI[row] = ri[0];
            outIdxF[row] = (float)ri[0];
        }
    }
}

// ---------------------------------------------------------------- gather
__global__ __launch_bounds__(256) void vq_gather_kernel(
    const float* __restrict__ x, const float* __restrict__ cb,
    const int* __restrict__ idxI, float* __restrict__ outQ,
    float* __restrict__ partial) {
    const int wave = threadIdx.x >> 6;
    const int lane = threadIdx.x & 63;
    const int row = blockIdx.x * 4 + wave;
    const int code = idxI[row];
    const float* xr = x + (size_t)row * DIM;
    const float* er = cb + (size_t)code * DIM;
    float* qr = outQ + (size_t)row * DIM;
    float s = 0.f;
#pragma unroll
    for (int i = 0; i < 2; ++i) {
        int d = lane * 8 + i * 4;
        float4 xv = *reinterpret_cast<const float4*>(xr + d);
        float4 ev = *reinterpret_cast<const float4*>(er + d);
        float4 dv = make_float4(ev.x - xv.x, ev.y - xv.y, ev.z - xv.z, ev.w - xv.w);
        *reinterpret_cast<float4*>(qr + d) = ev;
        s += dv.x * dv.x + dv.y * dv.y + dv.z * dv.z + dv.w * dv.w;
    }
#pragma unroll
    for (int off = 32; off > 0; off >>= 1) s += __shfl_xor(s, off);
    __shared__ float ws4[4];
    if (lane == 0) ws4[wave] = s;
    __syncthreads();
    if (threadIdx.x == 0)
        partial[blockIdx.x] = (ws4[0] + ws4[1]) + (ws4[2] + ws4[3]);
}

// ---------------------------------------------------------------- loss
__global__ __launch_bounds__(256) void vq_loss_kernel(const float* __restrict__ partial,
                                                      float* __restrict__ outLoss) {
    float s = 0.f;
    for (int i = threadIdx.x; i < 8192; i += 256) s += partial[i];
    __shared__ float sm[256];
    sm[threadIdx.x] = s;
    __syncthreads();
    for (int off = 128; off > 0; off >>= 1) {
        if (threadIdx.x < off) sm[threadIdx.x] += sm[threadIdx.x + off];
        __syncthreads();
    }
    if (threadIdx.x == 0)
        outLoss[0] = sm[0] * (1.0f + BETA) / 16777216.0f;
}

// ---------------------------------------------------------------- launch
extern "C" void kernel_launch(void* const* d_in, const int* in_sizes, int n_in,
                              void* d_out, int out_size, void* d_ws, size_t ws_size,
                              hipStream_t stream) {
    const float* x = (const float*)d_in[0];   // [32768, 512]
    const float* cb = (const float*)d_in[1];  // [8192, 512]
    float* out = (float*)d_out;

    // d_out scratch (rewritten by gather at the end)
    ushortT* xh = (ushortT*)out;
    ushortT* eh = (ushortT*)(out + SC_EH_F);
    unsigned* gCode = (unsigned*)(out + SC_GCODE_F);
    unsigned* gCnt = (unsigned*)(out + SC_GCNT_F);

    float* xx = (float*)d_ws + WS_XX_OFF;
    int* idxI = (int*)d_ws + WS_IDX_OFF;
    float* partial = (float*)d_ws + WS_PART_OFF;
    int* fixcnt = (int*)d_ws + WS_CNT_OFF;
    int* fixlist = (int*)d_ws + WS_LIST_OFF;

    hipMemsetAsync(fixcnt, 0, sizeof(int), stream);
    hipLaunchKernelGGL(vq_prep, dim3(10240), dim3(256), 0, stream, x, cb, xh, eh);
    hipLaunchKernelGGL(vq_xx_kernel, dim3(N_ROWS / 4), dim3(256), 0, stream, x, xx);
    hipLaunchKernelGGL(vq_margmin, dim3(N_ROWS / BM), dim3(512), 0, stream,
                       xh, eh, xx, gCode, gCnt, fixcnt, fixlist);
    hipLaunchKernelGGL(vq_refine, dim3(N_ROWS / 4), dim3(256), 0, stream,
                       x, cb, xx, gCode, gCnt, out + IDX_OFF, idxI);
    hipLaunchKernelGGL(vq_fixup_kernel, dim3(256), dim3(256), 0, stream,
                       x, cb, xx, fixcnt, fixlist, out + IDX_OFF, idxI);
    hipLaunchKernelGGL(vq_gather_kernel, dim3(N_ROWS / 4), dim3(256), 0, stream,
                       x, cb, idxI, out, partial);
    hipLaunchKernelGGL(vq_loss_kernel, dim3(1), dim3(256), 0, stream,
                       partial, out + LOSS_OFF);
}